// Round 11
// baseline (774.783 us; speedup 1.0000x reference)
//
#include <hip/hip_runtime.h>
#include <math.h>

#define NBATCH 512
#define TSTEPS 10
#define NIMG   5120   // NBATCH*TSTEPS
#define FEAT   616
#define NEDGE  8192

#define INV1 (1.0/(512.0*1600.0))   // BN1 count (conv1 out 40x40)
#define INV2 (1.0/(512.0*400.0))    // BN2 count (conv2 out 20x20)

__device__ __forceinline__ float sigf(float x){ return 1.f/(1.f + expf(-x)); }

// ---------------- prep: weight transposes + zero BN stats ----------------
__global__ void prep_kernel(const float* __restrict__ s1wl, const float* __restrict__ s1wr,
                            const float* __restrict__ s2wl, const float* __restrict__ s2wr,
                            const float* __restrict__ wih,  const float* __restrict__ whh,
                            const float* __restrict__ vw1,  const float* __restrict__ cw1,
                            const float* __restrict__ vw2,  const float* __restrict__ cw2,
                            float* __restrict__ wlT, float* __restrict__ wrT,
                            float* __restrict__ wl2T, float* __restrict__ wr2T,
                            float* __restrict__ wihT, float* __restrict__ whhT,
                            float* __restrict__ w1vT, float* __restrict__ w1cT,
                            float* __restrict__ w2vT, float* __restrict__ w2cT,
                            double* __restrict__ stats)
{
  int idx = blockIdx.x*256 + threadIdx.x;
  if (idx < 39424){ wlT[(idx%616)*64 + idx/616] = s1wl[idx]; return; }
  idx -= 39424;
  if (idx < 39424){ wrT[(idx%616)*64 + idx/616] = s1wr[idx]; return; }
  idx -= 39424;
  if (idx < 2048){ wl2T[(idx%64)*32 + idx/64] = s2wl[idx]; return; }
  idx -= 2048;
  if (idx < 2048){ wr2T[(idx%64)*32 + idx/64] = s2wr[idx]; return; }
  idx -= 2048;
  if (idx < 8192){ wihT[(idx%32)*256 + idx/32] = wih[idx]; return; }
  idx -= 8192;
  if (idx < 16384){ whhT[(idx%64)*256 + idx/64] = whh[idx]; return; }
  idx -= 16384;
  // conv weights -> [ci][k][co] so a wave-uniform co-group address can s_load
  if (idx < 720){  // vw1: 16co x 5ci x 9k
    int co = idx & 15, k = (idx >> 4) % 9, ci = idx / 144;
    w1vT[idx] = vw1[(co*5 + ci)*9 + k]; return;
  }
  idx -= 720;
  if (idx < 144){  // cw1: 16co x 1ci x 9k
    int co = idx & 15, k = idx >> 4;
    w1cT[idx] = cw1[co*9 + k]; return;
  }
  idx -= 144;
  if (idx < 2304){ // vw2: 16co x 16ci x 9k
    int co = idx & 15, k = (idx >> 4) % 9, ci = idx / 144;
    w2vT[idx] = vw2[(co*16 + ci)*9 + k]; return;
  }
  idx -= 2304;
  if (idx < 1152){ // cw2: 8co x 16ci x 9k
    int co = idx & 7, k = (idx >> 3) % 9, ci = idx / 72;
    w2cT[idx] = cw2[(co*16 + ci)*9 + k]; return;
  }
  idx -= 1152;
  if (idx < 1280){ stats[idx] = 0.0; }
}

// ---------------- CSR build for scatter-max (dst-grouped) ----------------
__global__ void csr_kernel(const int* __restrict__ edges, int* __restrict__ row_start,
                           int* __restrict__ adj)
{
  __shared__ int cnt_s[512];
  __shared__ int scan_s[512];
  const int tid = threadIdx.x;
  const int* src = edges;
  const int* dst = edges + NEDGE;
  cnt_s[tid] = 0;
  __syncthreads();
  for (int e = tid; e < NEDGE; e += 512) atomicAdd(&cnt_s[dst[e]], 1);
  __syncthreads();
  int v = cnt_s[tid];
  scan_s[tid] = v;
  __syncthreads();
  for (int off = 1; off < 512; off <<= 1){
    int add = (tid >= off) ? scan_s[tid - off] : 0;
    __syncthreads();
    scan_s[tid] += add;
    __syncthreads();
  }
  int start = scan_s[tid] - v;
  row_start[tid] = start;
  if (tid == 511) row_start[512] = scan_s[511];
  cnt_s[tid] = start;   // reuse as cursor
  __syncthreads();
  for (int e = tid; e < NEDGE; e += 512){
    int d = dst[e];
    int pos = atomicAdd(&cnt_s[d], 1);
    adj[pos] = src[e];
  }
}

// ---------------- conv1 (3x3 SAME, CIN->16), SINGLE PASS, SGPR weights ----------------
// R8/R9-proven: 249us, VALUBusy 82%, conflicts 1.17e7. DO NOT TOUCH.
template<int CIN>
__launch_bounds__(256)
__global__ void conv1_kernel(const float* __restrict__ in, const float* __restrict__ wT,
                             double* __restrict__ stats, float* __restrict__ premax)
{
  constexpr int INT = CIN*936;                 // 18 rows x 52 floats
  constexpr int SMF = (INT > 4608) ? INT : 4608;
  __shared__ __attribute__((aligned(16))) float smem[SMF];
  float* in_t = smem;               // [ci][18][4][12], row stride 52
  float* red  = smem;               // [16][64] s + [16][64] q = 2048 (post-barrier alias)
  float* plds = smem + 2048;        // [16][8][20] = 2560 pool staging
  const int tid = threadIdx.x;
  const int bid = blockIdx.x;
  const int img = bid / 3, strip = bid % 3;
  const int y0 = strip * 16;
  const int t = img % TSTEPS;
  const float* imgp = in + (size_t)img * CIN * 1600;

  // stage input halo, col-blocked: group g holds global cols g*10-1 .. g*10+10
  for (int ci = 0; ci < CIN; ci++){
    const float* ip = imgp + ci*1600;
    float* ot = &in_t[ci*936];
    for (int idx = tid; idx < 864; idx += 256){   // 864 = 18 x 48 write slots
      int r = idx / 48, w = idx % 48;
      int g = w / 12, c = w % 12;
      int gy = y0 + r - 1, gx = g*10 + c - 1;
      float v = 0.f;
      if ((unsigned)gy < 40u && (unsigned)gx < 40u) v = ip[gy*40 + gx];
      ot[r*52 + g*12 + c] = v;
    }
  }
  __syncthreads();

  const int lane = tid & 63;
  const int co0 = __builtin_amdgcn_readfirstlane(tid >> 6) * 4;   // wave-uniform
  const int row = lane & 15, g = lane >> 4;    // 16 rows x 4 groups of 10 px
  const int gy = y0 + row;
  const bool act = gy < 40;

  float acc[10][4];
  #pragma unroll
  for (int i = 0; i < 10; i++)
    #pragma unroll
    for (int j = 0; j < 4; j++) acc[i][j] = 0.f;

  for (int ci = 0; ci < CIN; ci++){
    const float* wp = wT + ci*144 + co0;       // scalar address -> s_load
    float4 sw[9];
    #pragma unroll
    for (int k = 0; k < 9; k++) sw[k] = *(const float4*)(wp + k*16);
    const float* rbase = &in_t[ci*936 + row*52 + g*12];
    #pragma unroll
    for (int dy = 0; dy < 3; dy++){
      float v[12];
      const float* rp = rbase + dy*52;
      const float4 a = *(const float4*)rp;
      const float4 b = *(const float4*)(rp + 4);
      const float4 c = *(const float4*)(rp + 8);
      v[0] = a.x; v[1]  = a.y; v[2]  = a.z; v[3]  = a.w;
      v[4] = b.x; v[5]  = b.y; v[6]  = b.z; v[7]  = b.w;
      v[8] = c.x; v[9]  = c.y; v[10] = c.z; v[11] = c.w;
      #pragma unroll
      for (int dx = 0; dx < 3; dx++){
        const float4 wv = sw[dy*3 + dx];
        #pragma unroll
        for (int p = 0; p < 10; p++){
          float iv = v[p + dx];
          acc[p][0] += iv*wv.x; acc[p][1] += iv*wv.y;
          acc[p][2] += iv*wv.z; acc[p][3] += iv*wv.w;
        }
      }
    }
  }

  __syncthreads();   // all waves done reading in_t -> red/plds may overwrite

  // (a) BN stats partials
  #pragma unroll
  for (int cl = 0; cl < 4; cl++){
    float s = 0.f, q = 0.f;
    #pragma unroll
    for (int p = 0; p < 10; p++){
      float a = acc[p][cl];
      s += a; q += a*a;
    }
    red[(co0 + cl)*64 + lane]        = act ? s : 0.f;
    red[1024 + (co0 + cl)*64 + lane] = act ? q : 0.f;
  }
  // (b) RAW 2x2 maxpool -> plds (row partner = lane^1)
  #pragma unroll
  for (int cl = 0; cl < 4; cl++){
    float hp[5];
    #pragma unroll
    for (int j = 0; j < 5; j++) hp[j] = fmaxf(acc[2*j][cl], acc[2*j + 1][cl]);
    float op[5];
    #pragma unroll
    for (int j = 0; j < 5; j++) op[j] = __shfl_xor(hp[j], 1, 64);
    if (!(row & 1)){
      #pragma unroll
      for (int j = 0; j < 5; j++)
        plds[(co0 + cl)*160 + (row >> 1)*20 + g*5 + j] = fmaxf(hp[j], op[j]);
    }
  }
  __syncthreads();

  // stats reduce: co = tid>>4 (0..15), seg = tid&15
  {
    const int co = tid >> 4, seg = tid & 15;
    float vs = 0.f, vq = 0.f;
    #pragma unroll
    for (int j = 0; j < 4; j++){
      vs += red[co*64 + seg*4 + j];
      vq += red[1024 + co*64 + seg*4 + j];
    }
    #pragma unroll
    for (int off = 8; off > 0; off >>= 1){
      vs += __shfl_down(vs, off, 16);
      vq += __shfl_down(vq, off, 16);
    }
    if (seg == 0){
      atomicAdd(&stats[(t*16 + co)*2 + 0], (double)vs);
      atomicAdd(&stats[(t*16 + co)*2 + 1], (double)vq);
    }
  }
  // pool writeout, coalesced (2560 = 10*256)
  {
    float* pb = premax + (size_t)img*6400;
    #pragma unroll
    for (int k = 0; k < 10; k++){
      int idx = tid + k*256;
      int co = idx / 160, rem = idx % 160;
      int py = rem / 20, col = rem % 20;
      int gpy = strip*8 + py;
      if (gpy < 20) pb[co*400 + gpy*20 + col] = plds[idx];
    }
  }
}

// ---------------- conv2 (3x3 SAME, 16->CO on 20x20), SINGLE PASS, SGPR weights ----------------
// BN1 params computed INLINE from stats (replicates bn_param's exact double
// math -> bit-identical); BN1+relu applied on load; RAW conv2 written back
// IN PLACE; BN2 stats emitted.
template<int CO>
__launch_bounds__(256)
__global__ void conv2_kernel(float* __restrict__ pooled, const float* __restrict__ wT,
                             const double* __restrict__ stats1,
                             const float* __restrict__ g1, const float* __restrict__ be1,
                             double* __restrict__ stats)
{
  constexpr int R = (CO == 16) ? 2 : 1;
  constexpr int P = (20/R) * 5;                 // 50 or 100
  __shared__ __attribute__((aligned(16))) float in_t[16*528];   // [16][22][24] halo
  __shared__ float bnp_s[32];                   // [ci][2] BN1 params
  const int tid = threadIdx.x;
  const int img = blockIdx.x;
  const int t = img % TSTEPS;
  const size_t ib = (size_t)img * 6400;

  if (tid < 16){
    double mean = stats1[(t*16 + tid)*2 + 0] * INV1;
    double var  = stats1[(t*16 + tid)*2 + 1] * INV1 - mean*mean;
    if (var < 0.0) var = 0.0;
    double sc = (double)g1[tid] / sqrt(var + 1e-5);
    bnp_s[tid*2 + 0] = (float)sc;
    bnp_s[tid*2 + 1] = be1[tid] - (float)(mean * sc);
  }
  __syncthreads();

  // staging: per-ci carry-chain; BN1 params wave-uniform per ci
  {
    const int r0 = tid / 24, c0 = tid % 24;     // 528 = 22 x 24
    for (int ci = 0; ci < 16; ci++){
      const float sc = bnp_s[ci*2 + 0];
      const float sh = bnp_s[ci*2 + 1];
      const float* ip = pooled + ib + ci*400;
      float* ot = &in_t[ci*528];
      int r = r0, c = c0;
      #pragma unroll
      for (int k = 0; k < 3; k++){              // ceil(528/256)=3
        int idx = tid + k*256;
        if (idx < 528){
          int gy = r - 1, gx = c - 1;
          float v = 0.f;
          if ((unsigned)gy < 20u && (unsigned)gx < 20u)
            v = fmaxf(sc*ip[gy*20 + gx] + sh, 0.f);
          ot[r*24 + c] = v;
        }
        r += 10; c += 16; if (c >= 24){ c -= 24; r += 1; }  // 256 = 10*24+16
      }
    }
  }
  __syncthreads();

  // wave-uniform co group; q spans one wave (CO=16) or a wave pair (CO=8)
  const int cog = (CO == 16) ? __builtin_amdgcn_readfirstlane(tid >> 6)
                             : __builtin_amdgcn_readfirstlane(tid >> 7);
  const int q   = (CO == 16) ? (tid & 63) : (tid & 127);
  const bool act = q < P;
  const int x4 = (q % 5) * 4, yb = (q / 5) * R;
  const int co0 = cog * 4;
  float acc[R][4][4];                           // [row][px][co]
  #pragma unroll
  for (int rr = 0; rr < R; rr++)
    #pragma unroll
    for (int i = 0; i < 4; i++)
      #pragma unroll
      for (int j = 0; j < 4; j++) acc[rr][i][j] = 0.f;

  if (act){
    for (int ci = 0; ci < 16; ci++){
      const float* wp = wT + ci*9*CO + co0;     // scalar address -> s_load
      float4 sw[9];
      #pragma unroll
      for (int k = 0; k < 9; k++) sw[k] = *(const float4*)(wp + k*CO);
      float v[R + 2][6];
      #pragma unroll
      for (int r = 0; r < R + 2; r++){
        const float* rp = &in_t[ci*528 + (yb + r)*24 + x4];
        const float4 a = *(const float4*)rp;
        const float2 b = *(const float2*)(rp + 4);
        v[r][0] = a.x; v[r][1] = a.y; v[r][2] = a.z; v[r][3] = a.w;
        v[r][4] = b.x; v[r][5] = b.y;
      }
      #pragma unroll
      for (int dy = 0; dy < 3; dy++)
        #pragma unroll
        for (int dx = 0; dx < 3; dx++){
          const float4 wv = sw[dy*3 + dx];
          #pragma unroll
          for (int rr = 0; rr < R; rr++){
            #pragma unroll
            for (int px = 0; px < 4; px++){
              float iv = v[rr + dy][px + dx];
              acc[rr][px][0] += iv*wv.x; acc[rr][px][1] += iv*wv.y;
              acc[rr][px][2] += iv*wv.z; acc[rr][px][3] += iv*wv.w;
            }
          }
        }
    }
    // write RAW conv2 back in place (own image region; reads finished pre-barrier)
    #pragma unroll
    for (int cl = 0; cl < 4; cl++)
      #pragma unroll
      for (int rr = 0; rr < R; rr++){
        float4 o4;
        o4.x = acc[rr][0][cl]; o4.y = acc[rr][1][cl];
        o4.z = acc[rr][2][cl]; o4.w = acc[rr][3][cl];
        *(float4*)&pooled[ib + (co0 + cl)*400 + (yb + rr)*20 + x4] = o4;
      }
  }
  __syncthreads();   // everyone done reading in_t; reuse it below

  if (act){
    #pragma unroll
    for (int cl = 0; cl < 4; cl++){
      float s = 0.f, qq = 0.f;
      #pragma unroll
      for (int rr = 0; rr < R; rr++)
        #pragma unroll
        for (int px = 0; px < 4; px++){
          float a = acc[rr][px][cl];
          s += a; qq += a*a;
        }
      in_t[(co0 + cl)*P + q]            = s;
      in_t[CO*P + (co0 + cl)*P + q]     = qq;
    }
  }
  __syncthreads();
  if (tid < CO*8){
    int co = tid >> 3, seg = tid & 7;
    float vs = 0.f, vq = 0.f;
    for (int j = seg; j < P; j += 8){
      vs += in_t[co*P + j];
      vq += in_t[CO*P + co*P + j];
    }
    #pragma unroll
    for (int off = 4; off > 0; off >>= 1){
      vs += __shfl_down(vs, off, 8);
      vq += __shfl_down(vq, off, 8);
    }
    if (seg == 0){
      atomicAdd(&stats[(t*CO + co)*2 + 0], (double)vs);
      atomicAdd(&stats[(t*CO + co)*2 + 1], (double)vq);
    }
  }
}

// ---------------- BN2 + relu + avgpool4 from raw conv2 (inline BN params) ----------------
// EMB=1 variant also fills the irrigation embedding slice of feats.
template<int CO, int EMB>
__global__ void bnavg_kernel(const float* __restrict__ raw,
                             const double* __restrict__ stats2,
                             const float* __restrict__ g2, const float* __restrict__ be2,
                             const int* __restrict__ irr, const float* __restrict__ emb,
                             float* __restrict__ feats, int featBase)
{
  __shared__ float bnp_s[32];
  const int img = blockIdx.x;
  const int t = img % TSTEPS, n = img / TSTEPS;
  const int tid = threadIdx.x;
  if (tid < CO){
    double mean = stats2[(t*CO + tid)*2 + 0] * INV2;
    double var  = stats2[(t*CO + tid)*2 + 1] * INV2 - mean*mean;
    if (var < 0.0) var = 0.0;
    double sc = (double)g2[tid] / sqrt(var + 1e-5);
    bnp_s[tid*2 + 0] = (float)sc;
    bnp_s[tid*2 + 1] = be2[tid] - (float)(mean * sc);
  }
  __syncthreads();
  for (int idx = tid; idx < CO*25; idx += 256){
    int co = idx / 25, q = idx % 25, py = q / 5, px = q % 5;
    float sc = bnp_s[co*2 + 0];
    float sh = bnp_s[co*2 + 1];
    const float* base = raw + (size_t)img*6400 + co*400 + (py*4)*20 + px*4;
    float s = 0.f;
    #pragma unroll
    for (int r = 0; r < 4; r++){
      float4 v = *(const float4*)(base + r*20);
      s += fmaxf(v.x*sc + sh, 0.f) + fmaxf(v.y*sc + sh, 0.f)
         + fmaxf(v.z*sc + sh, 0.f) + fmaxf(v.w*sc + sh, 0.f);
    }
    feats[(size_t)(t*NBATCH + n)*FEAT + featBase + idx] = s * 0.0625f;
  }
  if (EMB && tid < 16){
    feats[(size_t)(t*NBATCH + n)*FEAT + 600 + tid] = emb[irr[img]*16 + tid];
  }
}

// ---------------- SAGE1 with fused scatter-max gather: 616->64 ----------------
// 8 rows per block, 2 rows per thread in the matmul: each weight word
// (wlT/wrT) is loaded once per block and feeds 4 FMAs (was 2 rows/1 row ->
// 2 FMAs), halving the ~1.6 GB of weight re-read traffic. fmaxf gather is
// order-independent (exact); per-output FMA order (f ascending, ar then xr)
// unchanged -> bit-exact vs R10.
__launch_bounds__(256)
__global__ void sage1_kernel(const float* __restrict__ feats,
                             const int* __restrict__ row_start, const int* __restrict__ adj,
                             const float* __restrict__ wlT, const float* __restrict__ wrT,
                             const float* __restrict__ bl, float* __restrict__ x1)
{
  __shared__ float xr[8][616];
  __shared__ float ar[8][616];
  const int tid = threadIdx.x;
  const int bid = blockIdx.x;
  const int row0 = bid*8;
  const int t = row0 / NBATCH;                 // 8 | NBATCH -> same t for all 8 rows
  const int n0 = row0 - t*NBATCH;
  const float* fb = feats + (size_t)t*NBATCH*FEAT;

  for (int idx = tid; idx < 8*616; idx += 256){
    int r = idx / 616, f = idx % 616;
    xr[r][f] = feats[(size_t)(row0 + r)*FEAT + f];
  }
  for (int r = 0; r < 8; r++){
    const int n = n0 + r;
    const int rs = row_start[n], re = row_start[n + 1];
    const int deg = re - rs;
    for (int f = tid; f < 616; f += 256){
      float m = -1e30f;
      for (int j = 0; j < deg; j++){
        int s = adj[rs + j];
        m = fmaxf(m, fb[(size_t)s*FEAT + f]);
      }
      ar[r][f] = (deg > 0) ? m : 0.f;
    }
  }
  __syncthreads();
  const int o = tid & 63, wid = tid >> 6;
  const int r0 = wid*2;                        // 4 waves x 2 rows = 8 rows
  float a0 = bl[o], a1 = bl[o];
  #pragma unroll 4
  for (int f = 0; f < 616; f++){
    float wl_ = wlT[f*64 + o];
    float wr_ = wrT[f*64 + o];
    a0 += ar[r0    ][f]*wl_ + xr[r0    ][f]*wr_;
    a1 += ar[r0 + 1][f]*wl_ + xr[r0 + 1][f]*wr_;
  }
  x1[(size_t)(row0 + r0    )*64 + o] = fmaxf(a0, 0.f);
  x1[(size_t)(row0 + r0 + 1)*64 + o] = fmaxf(a1, 0.f);
}

// ---------------- SAGE2: 64->32 with its own scatter-max ----------------
__launch_bounds__(64)
__global__ void sage2_kernel(const float* __restrict__ x1, const int* __restrict__ row_start,
                             const int* __restrict__ adj, const float* __restrict__ wl2T,
                             const float* __restrict__ wr2T, const float* __restrict__ bl2,
                             float* __restrict__ x2)
{
  __shared__ float am[64], xm[64];
  __shared__ int adjs[192];
  const int bid = blockIdx.x;
  const int t = bid / NBATCH, n = bid % NBATCH;
  const int lane = threadIdx.x;
  const int rs = row_start[n], re = row_start[n + 1];
  const int deg = re - rs;
  for (int i = lane; i < deg && i < 192; i += 64) adjs[i] = adj[rs + i];
  __syncthreads();
  const float* xb = x1 + (size_t)t*NBATCH*64;
  float m = -1e30f;
  for (int j = 0; j < deg; j++){
    int s = (j < 192) ? adjs[j] : adj[rs + j];
    m = fmaxf(m, xb[s*64 + lane]);
  }
  am[lane] = (deg > 0) ? m : 0.f;
  xm[lane] = xb[n*64 + lane];
  __syncthreads();
  if (lane < 32){
    float acc = bl2[lane];
    #pragma unroll 4
    for (int f = 0; f < 64; f++){
      acc += am[f]*wl2T[f*32 + lane] + xm[f]*wr2T[f*32 + lane];
    }
    x2[(size_t)(t*NBATCH + n)*32 + lane] = fmaxf(acc, 0.f);
  }
}

// ---------------- fused LSTM (per-sample) + final FC ----------------
__launch_bounds__(256)
__global__ void lstm_kernel(const float* __restrict__ x2, const float* __restrict__ wihT,
                            const float* __restrict__ whhT, const float* __restrict__ bih,
                            const float* __restrict__ bhh, const float* __restrict__ fcw,
                            const float* __restrict__ fcb, float* __restrict__ out)
{
  __shared__ float xb[32], hb[64], cbuf[64], zb[256];
  const int n = blockIdx.x;
  const int tid = threadIdx.x;
  if (tid < 64){ hb[tid] = 0.f; cbuf[tid] = 0.f; }
  __syncthreads();
  const float bsum = bih[tid] + bhh[tid];
  for (int t = 0; t < TSTEPS; t++){
    if (tid < 32) xb[tid] = x2[(size_t)(t*NBATCH + n)*32 + tid];
    __syncthreads();
    float acc = bsum;
    #pragma unroll 8
    for (int k = 0; k < 32; k++) acc += xb[k]*wihT[k*256 + tid];
    #pragma unroll 8
    for (int k = 0; k < 64; k++) acc += hb[k]*whhT[k*256 + tid];
    zb[tid] = acc;
    __syncthreads();
    if (tid < 64){
      float zi = zb[tid], zf = zb[64 + tid], zg = zb[128 + tid], zo = zb[192 + tid];
      float c = sigf(zf)*cbuf[tid] + sigf(zi)*tanhf(zg);
      cbuf[tid] = c;
      hb[tid] = sigf(zo)*tanhf(c);
    }
    __syncthreads();
  }
  if (tid < 64){
    float v = hb[tid]*fcw[tid];
    #pragma unroll
    for (int off = 32; off > 0; off >>= 1) v += __shfl_down(v, off, 64);
    if (tid == 0) out[n] = v + fcb[0];
  }
}

extern "C" void kernel_launch(void* const* d_in, const int* in_sizes, int n_in,
                              void* d_out, int out_size, void* d_ws, size_t ws_size,
                              hipStream_t stream)
{
  const float* veg  = (const float*)d_in[0];
  const float* cwsi = (const float*)d_in[1];
  const int*   irr  = (const int*)d_in[2];
  const int*   eidx = (const int*)d_in[3];
  const float* vw1  = (const float*)d_in[4];
  const float* vg1  = (const float*)d_in[6];
  const float* vbe1 = (const float*)d_in[7];
  const float* vw2  = (const float*)d_in[8];
  const float* vg2  = (const float*)d_in[10];
  const float* vbe2 = (const float*)d_in[11];
  const float* cw1  = (const float*)d_in[12];
  const float* cg1  = (const float*)d_in[14];
  const float* cbe1 = (const float*)d_in[15];
  const float* cw2  = (const float*)d_in[16];
  const float* cg2  = (const float*)d_in[18];
  const float* cbe2 = (const float*)d_in[19];
  const float* emb  = (const float*)d_in[20];
  const float* s1wl = (const float*)d_in[21];
  const float* s1bl = (const float*)d_in[22];
  const float* s1wr = (const float*)d_in[23];
  const float* s2wl = (const float*)d_in[24];
  const float* s2bl = (const float*)d_in[25];
  const float* s2wr = (const float*)d_in[26];
  const float* wih  = (const float*)d_in[27];
  const float* whh  = (const float*)d_in[28];
  const float* bih  = (const float*)d_in[29];
  const float* bhh  = (const float*)d_in[30];
  const float* fcw  = (const float*)d_in[31];
  const float* fcb  = (const float*)d_in[32];
  float* out = (float*)d_out;

  float* ws = (float*)d_ws;
  size_t off = 0;
  float* pooled = ws + off; off += (size_t)NIMG*6400;      // 131 MB premax / raw conv2
  float* feats  = ws + off; off += (size_t)NIMG*FEAT;
  float* x1     = ws + off; off += (size_t)NIMG*64;
  float* x2     = ws + off; off += (size_t)NIMG*32;
  float* wlT    = ws + off; off += 39424;
  float* wrT    = ws + off; off += 39424;
  float* wl2T   = ws + off; off += 2048;
  float* wr2T   = ws + off; off += 2048;
  float* wihT   = ws + off; off += 8192;
  float* whhT   = ws + off; off += 16384;
  float* w1vT   = ws + off; off += 720;
  float* w1cT   = ws + off; off += 144;
  float* w2vT   = ws + off; off += 2304;
  float* w2cT   = ws + off; off += 1152;
  off = (off + 1) & ~(size_t)1;                            // 8B align for doubles
  double* stats = (double*)(ws + off); off += 2560;        // 1280 doubles
  int* row_start= (int*)(ws + off); off += 513;
  int* adj      = (int*)(ws + off); off += 8192;
  (void)in_sizes; (void)n_in; (void)out_size; (void)ws_size;

  prep_kernel<<<442, 256, 0, stream>>>(s1wl, s1wr, s2wl, s2wr, wih, whh,
                                       vw1, cw1, vw2, cw2,
                                       wlT, wrT, wl2T, wr2T, wihT, whhT,
                                       w1vT, w1cT, w2vT, w2cT, stats);
  csr_kernel<<<1, 512, 0, stream>>>(eidx, row_start, adj);

  double* stV1 = stats;        // veg BN1
  double* stV2 = stats + 320;  // veg BN2
  double* stC1 = stats + 640;  // cwsi BN1
  double* stC2 = stats + 960;  // cwsi BN2

  // --- veg CNN (single conv pass each; BN params inlined from stats) ---
  conv1_kernel<5><<<NIMG*3, 256, 0, stream>>>(veg, w1vT, stV1, pooled);
  conv2_kernel<16><<<NIMG, 256, 0, stream>>>(pooled, w2vT, stV1, vg1, vbe1, stV2);
  bnavg_kernel<16,0><<<NIMG, 256, 0, stream>>>(pooled, stV2, vg2, vbe2,
                                               irr, emb, feats, 0);

  // --- cwsi CNN ---
  conv1_kernel<1><<<NIMG*3, 256, 0, stream>>>(cwsi, w1cT, stC1, pooled);
  conv2_kernel<8><<<NIMG, 256, 0, stream>>>(pooled, w2cT, stC1, cg1, cbe1, stC2);
  bnavg_kernel<8,1><<<NIMG, 256, 0, stream>>>(pooled, stC2, cg2, cbe2,
                                              irr, emb, feats, 400);

  // --- features tail (agg fused into sage1; 8 rows/block) ---
  sage1_kernel<<<NIMG/8, 256, 0, stream>>>(feats, row_start, adj, wlT, wrT, s1bl, x1);
  sage2_kernel<<<NIMG, 64, 0, stream>>>(x1, row_start, adj, wl2T, wr2T, s2bl, x2);
  lstm_kernel<<<NBATCH, 256, 0, stream>>>(x2, wihT, whhT, bih, bhh, fcw, fcb, out);
}

// Round 12
// 751.514 us; speedup vs baseline: 1.0310x; 1.0310x over previous
//
#include <hip/hip_runtime.h>
#include <math.h>

#define NBATCH 512
#define TSTEPS 10
#define NIMG   5120   // NBATCH*TSTEPS
#define FEAT   616
#define NEDGE  8192

#define INV1 (1.0/(512.0*1600.0))   // BN1 count (conv1 out 40x40)
#define INV2 (1.0/(512.0*400.0))    // BN2 count (conv2 out 20x20)

__device__ __forceinline__ float sigf(float x){ return 1.f/(1.f + expf(-x)); }

// ---------------- prep: weight transposes + zero BN stats ----------------
__global__ void prep_kernel(const float* __restrict__ s1wl, const float* __restrict__ s1wr,
                            const float* __restrict__ s2wl, const float* __restrict__ s2wr,
                            const float* __restrict__ wih,  const float* __restrict__ whh,
                            const float* __restrict__ vw1,  const float* __restrict__ cw1,
                            const float* __restrict__ vw2,  const float* __restrict__ cw2,
                            float* __restrict__ wlT, float* __restrict__ wrT,
                            float* __restrict__ wl2T, float* __restrict__ wr2T,
                            float* __restrict__ wihT, float* __restrict__ whhT,
                            float* __restrict__ w1vT, float* __restrict__ w1cT,
                            float* __restrict__ w2vT, float* __restrict__ w2cT,
                            double* __restrict__ stats)
{
  int idx = blockIdx.x*256 + threadIdx.x;
  if (idx < 39424){ wlT[(idx%616)*64 + idx/616] = s1wl[idx]; return; }
  idx -= 39424;
  if (idx < 39424){ wrT[(idx%616)*64 + idx/616] = s1wr[idx]; return; }
  idx -= 39424;
  if (idx < 2048){ wl2T[(idx%64)*32 + idx/64] = s2wl[idx]; return; }
  idx -= 2048;
  if (idx < 2048){ wr2T[(idx%64)*32 + idx/64] = s2wr[idx]; return; }
  idx -= 2048;
  if (idx < 8192){ wihT[(idx%32)*256 + idx/32] = wih[idx]; return; }
  idx -= 8192;
  if (idx < 16384){ whhT[(idx%64)*256 + idx/64] = whh[idx]; return; }
  idx -= 16384;
  // conv weights -> [ci][k][co] so a wave-uniform co-group address can s_load
  if (idx < 720){  // vw1: 16co x 5ci x 9k
    int co = idx & 15, k = (idx >> 4) % 9, ci = idx / 144;
    w1vT[idx] = vw1[(co*5 + ci)*9 + k]; return;
  }
  idx -= 720;
  if (idx < 144){  // cw1: 16co x 1ci x 9k
    int co = idx & 15, k = idx >> 4;
    w1cT[idx] = cw1[co*9 + k]; return;
  }
  idx -= 144;
  if (idx < 2304){ // vw2: 16co x 16ci x 9k
    int co = idx & 15, k = (idx >> 4) % 9, ci = idx / 144;
    w2vT[idx] = vw2[(co*16 + ci)*9 + k]; return;
  }
  idx -= 2304;
  if (idx < 1152){ // cw2: 8co x 16ci x 9k
    int co = idx & 7, k = (idx >> 3) % 9, ci = idx / 72;
    w2cT[idx] = cw2[(co*16 + ci)*9 + k]; return;
  }
  idx -= 1152;
  if (idx < 1280){ stats[idx] = 0.0; }
}

// ---------------- CSR build for scatter-max (dst-grouped) ----------------
__global__ void csr_kernel(const int* __restrict__ edges, int* __restrict__ row_start,
                           int* __restrict__ adj)
{
  __shared__ int cnt_s[512];
  __shared__ int scan_s[512];
  const int tid = threadIdx.x;
  const int* src = edges;
  const int* dst = edges + NEDGE;
  cnt_s[tid] = 0;
  __syncthreads();
  for (int e = tid; e < NEDGE; e += 512) atomicAdd(&cnt_s[dst[e]], 1);
  __syncthreads();
  int v = cnt_s[tid];
  scan_s[tid] = v;
  __syncthreads();
  for (int off = 1; off < 512; off <<= 1){
    int add = (tid >= off) ? scan_s[tid - off] : 0;
    __syncthreads();
    scan_s[tid] += add;
    __syncthreads();
  }
  int start = scan_s[tid] - v;
  row_start[tid] = start;
  if (tid == 511) row_start[512] = scan_s[511];
  cnt_s[tid] = start;   // reuse as cursor
  __syncthreads();
  for (int e = tid; e < NEDGE; e += 512){
    int d = dst[e];
    int pos = atomicAdd(&cnt_s[d], 1);
    adj[pos] = src[e];
  }
}

// ---------------- conv1 (3x3 SAME, CIN->16), SINGLE PASS, SGPR weights ----------------
// R8/R9-proven: 249us, VALUBusy 82%, conflicts 1.17e7. DO NOT TOUCH.
template<int CIN>
__launch_bounds__(256)
__global__ void conv1_kernel(const float* __restrict__ in, const float* __restrict__ wT,
                             double* __restrict__ stats, float* __restrict__ premax)
{
  constexpr int INT = CIN*936;                 // 18 rows x 52 floats
  constexpr int SMF = (INT > 4608) ? INT : 4608;
  __shared__ __attribute__((aligned(16))) float smem[SMF];
  float* in_t = smem;               // [ci][18][4][12], row stride 52
  float* red  = smem;               // [16][64] s + [16][64] q = 2048 (post-barrier alias)
  float* plds = smem + 2048;        // [16][8][20] = 2560 pool staging
  const int tid = threadIdx.x;
  const int bid = blockIdx.x;
  const int img = bid / 3, strip = bid % 3;
  const int y0 = strip * 16;
  const int t = img % TSTEPS;
  const float* imgp = in + (size_t)img * CIN * 1600;

  // stage input halo, col-blocked: group g holds global cols g*10-1 .. g*10+10
  for (int ci = 0; ci < CIN; ci++){
    const float* ip = imgp + ci*1600;
    float* ot = &in_t[ci*936];
    for (int idx = tid; idx < 864; idx += 256){   // 864 = 18 x 48 write slots
      int r = idx / 48, w = idx % 48;
      int g = w / 12, c = w % 12;
      int gy = y0 + r - 1, gx = g*10 + c - 1;
      float v = 0.f;
      if ((unsigned)gy < 40u && (unsigned)gx < 40u) v = ip[gy*40 + gx];
      ot[r*52 + g*12 + c] = v;
    }
  }
  __syncthreads();

  const int lane = tid & 63;
  const int co0 = __builtin_amdgcn_readfirstlane(tid >> 6) * 4;   // wave-uniform
  const int row = lane & 15, g = lane >> 4;    // 16 rows x 4 groups of 10 px
  const int gy = y0 + row;
  const bool act = gy < 40;

  float acc[10][4];
  #pragma unroll
  for (int i = 0; i < 10; i++)
    #pragma unroll
    for (int j = 0; j < 4; j++) acc[i][j] = 0.f;

  for (int ci = 0; ci < CIN; ci++){
    const float* wp = wT + ci*144 + co0;       // scalar address -> s_load
    float4 sw[9];
    #pragma unroll
    for (int k = 0; k < 9; k++) sw[k] = *(const float4*)(wp + k*16);
    const float* rbase = &in_t[ci*936 + row*52 + g*12];
    #pragma unroll
    for (int dy = 0; dy < 3; dy++){
      float v[12];
      const float* rp = rbase + dy*52;
      const float4 a = *(const float4*)rp;
      const float4 b = *(const float4*)(rp + 4);
      const float4 c = *(const float4*)(rp + 8);
      v[0] = a.x; v[1]  = a.y; v[2]  = a.z; v[3]  = a.w;
      v[4] = b.x; v[5]  = b.y; v[6]  = b.z; v[7]  = b.w;
      v[8] = c.x; v[9]  = c.y; v[10] = c.z; v[11] = c.w;
      #pragma unroll
      for (int dx = 0; dx < 3; dx++){
        const float4 wv = sw[dy*3 + dx];
        #pragma unroll
        for (int p = 0; p < 10; p++){
          float iv = v[p + dx];
          acc[p][0] += iv*wv.x; acc[p][1] += iv*wv.y;
          acc[p][2] += iv*wv.z; acc[p][3] += iv*wv.w;
        }
      }
    }
  }

  __syncthreads();   // all waves done reading in_t -> red/plds may overwrite

  // (a) BN stats partials
  #pragma unroll
  for (int cl = 0; cl < 4; cl++){
    float s = 0.f, q = 0.f;
    #pragma unroll
    for (int p = 0; p < 10; p++){
      float a = acc[p][cl];
      s += a; q += a*a;
    }
    red[(co0 + cl)*64 + lane]        = act ? s : 0.f;
    red[1024 + (co0 + cl)*64 + lane] = act ? q : 0.f;
  }
  // (b) RAW 2x2 maxpool -> plds (row partner = lane^1)
  #pragma unroll
  for (int cl = 0; cl < 4; cl++){
    float hp[5];
    #pragma unroll
    for (int j = 0; j < 5; j++) hp[j] = fmaxf(acc[2*j][cl], acc[2*j + 1][cl]);
    float op[5];
    #pragma unroll
    for (int j = 0; j < 5; j++) op[j] = __shfl_xor(hp[j], 1, 64);
    if (!(row & 1)){
      #pragma unroll
      for (int j = 0; j < 5; j++)
        plds[(co0 + cl)*160 + (row >> 1)*20 + g*5 + j] = fmaxf(hp[j], op[j]);
    }
  }
  __syncthreads();

  // stats reduce: co = tid>>4 (0..15), seg = tid&15
  {
    const int co = tid >> 4, seg = tid & 15;
    float vs = 0.f, vq = 0.f;
    #pragma unroll
    for (int j = 0; j < 4; j++){
      vs += red[co*64 + seg*4 + j];
      vq += red[1024 + co*64 + seg*4 + j];
    }
    #pragma unroll
    for (int off = 8; off > 0; off >>= 1){
      vs += __shfl_down(vs, off, 16);
      vq += __shfl_down(vq, off, 16);
    }
    if (seg == 0){
      atomicAdd(&stats[(t*16 + co)*2 + 0], (double)vs);
      atomicAdd(&stats[(t*16 + co)*2 + 1], (double)vq);
    }
  }
  // pool writeout, coalesced (2560 = 10*256)
  {
    float* pb = premax + (size_t)img*6400;
    #pragma unroll
    for (int k = 0; k < 10; k++){
      int idx = tid + k*256;
      int co = idx / 160, rem = idx % 160;
      int py = rem / 20, col = rem % 20;
      int gpy = strip*8 + py;
      if (gpy < 20) pb[co*400 + gpy*20 + col] = plds[idx];
    }
  }
}

// ---------------- conv2 (3x3 SAME, 16->CO on 20x20), SINGLE PASS, SGPR weights ----------------
// BN1 params computed INLINE from stats (replicates bn_param's exact double
// math -> bit-identical); BN1+relu applied on load; RAW conv2 written back
// IN PLACE; BN2 stats emitted.
template<int CO>
__launch_bounds__(256)
__global__ void conv2_kernel(float* __restrict__ pooled, const float* __restrict__ wT,
                             const double* __restrict__ stats1,
                             const float* __restrict__ g1, const float* __restrict__ be1,
                             double* __restrict__ stats)
{
  constexpr int R = (CO == 16) ? 2 : 1;
  constexpr int P = (20/R) * 5;                 // 50 or 100
  __shared__ __attribute__((aligned(16))) float in_t[16*528];   // [16][22][24] halo
  __shared__ float bnp_s[32];                   // [ci][2] BN1 params
  const int tid = threadIdx.x;
  const int img = blockIdx.x;
  const int t = img % TSTEPS;
  const size_t ib = (size_t)img * 6400;

  if (tid < 16){
    double mean = stats1[(t*16 + tid)*2 + 0] * INV1;
    double var  = stats1[(t*16 + tid)*2 + 1] * INV1 - mean*mean;
    if (var < 0.0) var = 0.0;
    double sc = (double)g1[tid] / sqrt(var + 1e-5);
    bnp_s[tid*2 + 0] = (float)sc;
    bnp_s[tid*2 + 1] = be1[tid] - (float)(mean * sc);
  }
  __syncthreads();

  // staging: per-ci carry-chain; BN1 params wave-uniform per ci
  {
    const int r0 = tid / 24, c0 = tid % 24;     // 528 = 22 x 24
    for (int ci = 0; ci < 16; ci++){
      const float sc = bnp_s[ci*2 + 0];
      const float sh = bnp_s[ci*2 + 1];
      const float* ip = pooled + ib + ci*400;
      float* ot = &in_t[ci*528];
      int r = r0, c = c0;
      #pragma unroll
      for (int k = 0; k < 3; k++){              // ceil(528/256)=3
        int idx = tid + k*256;
        if (idx < 528){
          int gy = r - 1, gx = c - 1;
          float v = 0.f;
          if ((unsigned)gy < 20u && (unsigned)gx < 20u)
            v = fmaxf(sc*ip[gy*20 + gx] + sh, 0.f);
          ot[r*24 + c] = v;
        }
        r += 10; c += 16; if (c >= 24){ c -= 24; r += 1; }  // 256 = 10*24+16
      }
    }
  }
  __syncthreads();

  // wave-uniform co group; q spans one wave (CO=16) or a wave pair (CO=8)
  const int cog = (CO == 16) ? __builtin_amdgcn_readfirstlane(tid >> 6)
                             : __builtin_amdgcn_readfirstlane(tid >> 7);
  const int q   = (CO == 16) ? (tid & 63) : (tid & 127);
  const bool act = q < P;
  const int x4 = (q % 5) * 4, yb = (q / 5) * R;
  const int co0 = cog * 4;
  float acc[R][4][4];                           // [row][px][co]
  #pragma unroll
  for (int rr = 0; rr < R; rr++)
    #pragma unroll
    for (int i = 0; i < 4; i++)
      #pragma unroll
      for (int j = 0; j < 4; j++) acc[rr][i][j] = 0.f;

  if (act){
    for (int ci = 0; ci < 16; ci++){
      const float* wp = wT + ci*9*CO + co0;     // scalar address -> s_load
      float4 sw[9];
      #pragma unroll
      for (int k = 0; k < 9; k++) sw[k] = *(const float4*)(wp + k*CO);
      float v[R + 2][6];
      #pragma unroll
      for (int r = 0; r < R + 2; r++){
        const float* rp = &in_t[ci*528 + (yb + r)*24 + x4];
        const float4 a = *(const float4*)rp;
        const float2 b = *(const float2*)(rp + 4);
        v[r][0] = a.x; v[r][1] = a.y; v[r][2] = a.z; v[r][3] = a.w;
        v[r][4] = b.x; v[r][5] = b.y;
      }
      #pragma unroll
      for (int dy = 0; dy < 3; dy++)
        #pragma unroll
        for (int dx = 0; dx < 3; dx++){
          const float4 wv = sw[dy*3 + dx];
          #pragma unroll
          for (int rr = 0; rr < R; rr++){
            #pragma unroll
            for (int px = 0; px < 4; px++){
              float iv = v[rr + dy][px + dx];
              acc[rr][px][0] += iv*wv.x; acc[rr][px][1] += iv*wv.y;
              acc[rr][px][2] += iv*wv.z; acc[rr][px][3] += iv*wv.w;
            }
          }
        }
    }
    // write RAW conv2 back in place (own image region; reads finished pre-barrier)
    #pragma unroll
    for (int cl = 0; cl < 4; cl++)
      #pragma unroll
      for (int rr = 0; rr < R; rr++){
        float4 o4;
        o4.x = acc[rr][0][cl]; o4.y = acc[rr][1][cl];
        o4.z = acc[rr][2][cl]; o4.w = acc[rr][3][cl];
        *(float4*)&pooled[ib + (co0 + cl)*400 + (yb + rr)*20 + x4] = o4;
      }
  }
  __syncthreads();   // everyone done reading in_t; reuse it below

  if (act){
    #pragma unroll
    for (int cl = 0; cl < 4; cl++){
      float s = 0.f, qq = 0.f;
      #pragma unroll
      for (int rr = 0; rr < R; rr++)
        #pragma unroll
        for (int px = 0; px < 4; px++){
          float a = acc[rr][px][cl];
          s += a; qq += a*a;
        }
      in_t[(co0 + cl)*P + q]            = s;
      in_t[CO*P + (co0 + cl)*P + q]     = qq;
    }
  }
  __syncthreads();
  if (tid < CO*8){
    int co = tid >> 3, seg = tid & 7;
    float vs = 0.f, vq = 0.f;
    for (int j = seg; j < P; j += 8){
      vs += in_t[co*P + j];
      vq += in_t[CO*P + co*P + j];
    }
    #pragma unroll
    for (int off = 4; off > 0; off >>= 1){
      vs += __shfl_down(vs, off, 8);
      vq += __shfl_down(vq, off, 8);
    }
    if (seg == 0){
      atomicAdd(&stats[(t*CO + co)*2 + 0], (double)vs);
      atomicAdd(&stats[(t*CO + co)*2 + 1], (double)vq);
    }
  }
}

// ---------------- BN2 + relu + avgpool4 from raw conv2 (inline BN params) ----------------
// EMB=1 variant also fills the irrigation embedding slice of feats.
template<int CO, int EMB>
__global__ void bnavg_kernel(const float* __restrict__ raw,
                             const double* __restrict__ stats2,
                             const float* __restrict__ g2, const float* __restrict__ be2,
                             const int* __restrict__ irr, const float* __restrict__ emb,
                             float* __restrict__ feats, int featBase)
{
  __shared__ float bnp_s[32];
  const int img = blockIdx.x;
  const int t = img % TSTEPS, n = img / TSTEPS;
  const int tid = threadIdx.x;
  if (tid < CO){
    double mean = stats2[(t*CO + tid)*2 + 0] * INV2;
    double var  = stats2[(t*CO + tid)*2 + 1] * INV2 - mean*mean;
    if (var < 0.0) var = 0.0;
    double sc = (double)g2[tid] / sqrt(var + 1e-5);
    bnp_s[tid*2 + 0] = (float)sc;
    bnp_s[tid*2 + 1] = be2[tid] - (float)(mean * sc);
  }
  __syncthreads();
  for (int idx = tid; idx < CO*25; idx += 256){
    int co = idx / 25, q = idx % 25, py = q / 5, px = q % 5;
    float sc = bnp_s[co*2 + 0];
    float sh = bnp_s[co*2 + 1];
    const float* base = raw + (size_t)img*6400 + co*400 + (py*4)*20 + px*4;
    float s = 0.f;
    #pragma unroll
    for (int r = 0; r < 4; r++){
      float4 v = *(const float4*)(base + r*20);
      s += fmaxf(v.x*sc + sh, 0.f) + fmaxf(v.y*sc + sh, 0.f)
         + fmaxf(v.z*sc + sh, 0.f) + fmaxf(v.w*sc + sh, 0.f);
    }
    feats[(size_t)(t*NBATCH + n)*FEAT + featBase + idx] = s * 0.0625f;
  }
  if (EMB && tid < 16){
    feats[(size_t)(t*NBATCH + n)*FEAT + 600 + tid] = emb[irr[img]*16 + tid];
  }
}

// ---------------- SAGE1 with fused scatter-max gather: 616->64 ----------------
// R10-proven form: 4 rows per block (1280 blocks, 19.7KB LDS). ar = neighbor
// max computed inline (same fmaxf order as the old agg kernel -> bit-exact);
// xr = own features. Then the matmul. R11's 8-row variant regressed (-23us):
// weights were already L2-resident, and halving block count starved the
// latency-bound gather of waves. DO NOT re-block.
__launch_bounds__(256)
__global__ void sage1_kernel(const float* __restrict__ feats,
                             const int* __restrict__ row_start, const int* __restrict__ adj,
                             const float* __restrict__ wlT, const float* __restrict__ wrT,
                             const float* __restrict__ bl, float* __restrict__ x1)
{
  __shared__ float xr[4][616];
  __shared__ float ar[4][616];
  const int tid = threadIdx.x;
  const int bid = blockIdx.x;
  const int row0 = bid*4;
  const int t = row0 / NBATCH;                 // 4 | NBATCH -> same t for all 4 rows
  const int n0 = row0 - t*NBATCH;
  const float* fb = feats + (size_t)t*NBATCH*FEAT;

  for (int idx = tid; idx < 4*616; idx += 256){
    int r = idx / 616, f = idx % 616;
    xr[r][f] = feats[(size_t)(row0 + r)*FEAT + f];
  }
  for (int r = 0; r < 4; r++){
    const int n = n0 + r;
    const int rs = row_start[n], re = row_start[n + 1];
    const int deg = re - rs;
    for (int f = tid; f < 616; f += 256){
      float m = -1e30f;
      for (int j = 0; j < deg; j++){
        int s = adj[rs + j];
        m = fmaxf(m, fb[(size_t)s*FEAT + f]);
      }
      ar[r][f] = (deg > 0) ? m : 0.f;
    }
  }
  __syncthreads();
  const int wid = tid >> 6, o = tid & 63;
  const int row = row0 + wid;
  float acc = bl[o];
  #pragma unroll 4
  for (int f = 0; f < 616; f++){
    acc += ar[wid][f]*wlT[f*64 + o] + xr[wid][f]*wrT[f*64 + o];
  }
  x1[(size_t)row*64 + o] = fmaxf(acc, 0.f);
}

// ---------------- SAGE2: 64->32 with its own scatter-max ----------------
__launch_bounds__(64)
__global__ void sage2_kernel(const float* __restrict__ x1, const int* __restrict__ row_start,
                             const int* __restrict__ adj, const float* __restrict__ wl2T,
                             const float* __restrict__ wr2T, const float* __restrict__ bl2,
                             float* __restrict__ x2)
{
  __shared__ float am[64], xm[64];
  __shared__ int adjs[192];
  const int bid = blockIdx.x;
  const int t = bid / NBATCH, n = bid % NBATCH;
  const int lane = threadIdx.x;
  const int rs = row_start[n], re = row_start[n + 1];
  const int deg = re - rs;
  for (int i = lane; i < deg && i < 192; i += 64) adjs[i] = adj[rs + i];
  __syncthreads();
  const float* xb = x1 + (size_t)t*NBATCH*64;
  float m = -1e30f;
  for (int j = 0; j < deg; j++){
    int s = (j < 192) ? adjs[j] : adj[rs + j];
    m = fmaxf(m, xb[s*64 + lane]);
  }
  am[lane] = (deg > 0) ? m : 0.f;
  xm[lane] = xb[n*64 + lane];
  __syncthreads();
  if (lane < 32){
    float acc = bl2[lane];
    #pragma unroll 4
    for (int f = 0; f < 64; f++){
      acc += am[f]*wl2T[f*32 + lane] + xm[f]*wr2T[f*32 + lane];
    }
    x2[(size_t)(t*NBATCH + n)*32 + lane] = fmaxf(acc, 0.f);
  }
}

// ---------------- fused LSTM (per-sample) + final FC ----------------
__launch_bounds__(256)
__global__ void lstm_kernel(const float* __restrict__ x2, const float* __restrict__ wihT,
                            const float* __restrict__ whhT, const float* __restrict__ bih,
                            const float* __restrict__ bhh, const float* __restrict__ fcw,
                            const float* __restrict__ fcb, float* __restrict__ out)
{
  __shared__ float xb[32], hb[64], cbuf[64], zb[256];
  const int n = blockIdx.x;
  const int tid = threadIdx.x;
  if (tid < 64){ hb[tid] = 0.f; cbuf[tid] = 0.f; }
  __syncthreads();
  const float bsum = bih[tid] + bhh[tid];
  for (int t = 0; t < TSTEPS; t++){
    if (tid < 32) xb[tid] = x2[(size_t)(t*NBATCH + n)*32 + tid];
    __syncthreads();
    float acc = bsum;
    #pragma unroll 8
    for (int k = 0; k < 32; k++) acc += xb[k]*wihT[k*256 + tid];
    #pragma unroll 8
    for (int k = 0; k < 64; k++) acc += hb[k]*whhT[k*256 + tid];
    zb[tid] = acc;
    __syncthreads();
    if (tid < 64){
      float zi = zb[tid], zf = zb[64 + tid], zg = zb[128 + tid], zo = zb[192 + tid];
      float c = sigf(zf)*cbuf[tid] + sigf(zi)*tanhf(zg);
      cbuf[tid] = c;
      hb[tid] = sigf(zo)*tanhf(c);
    }
    __syncthreads();
  }
  if (tid < 64){
    float v = hb[tid]*fcw[tid];
    #pragma unroll
    for (int off = 32; off > 0; off >>= 1) v += __shfl_down(v, off, 64);
    if (tid == 0) out[n] = v + fcb[0];
  }
}

extern "C" void kernel_launch(void* const* d_in, const int* in_sizes, int n_in,
                              void* d_out, int out_size, void* d_ws, size_t ws_size,
                              hipStream_t stream)
{
  const float* veg  = (const float*)d_in[0];
  const float* cwsi = (const float*)d_in[1];
  const int*   irr  = (const int*)d_in[2];
  const int*   eidx = (const int*)d_in[3];
  const float* vw1  = (const float*)d_in[4];
  const float* vg1  = (const float*)d_in[6];
  const float* vbe1 = (const float*)d_in[7];
  const float* vw2  = (const float*)d_in[8];
  const float* vg2  = (const float*)d_in[10];
  const float* vbe2 = (const float*)d_in[11];
  const float* cw1  = (const float*)d_in[12];
  const float* cg1  = (const float*)d_in[14];
  const float* cbe1 = (const float*)d_in[15];
  const float* cw2  = (const float*)d_in[16];
  const float* cg2  = (const float*)d_in[18];
  const float* cbe2 = (const float*)d_in[19];
  const float* emb  = (const float*)d_in[20];
  const float* s1wl = (const float*)d_in[21];
  const float* s1bl = (const float*)d_in[22];
  const float* s1wr = (const float*)d_in[23];
  const float* s2wl = (const float*)d_in[24];
  const float* s2bl = (const float*)d_in[25];
  const float* s2wr = (const float*)d_in[26];
  const float* wih  = (const float*)d_in[27];
  const float* whh  = (const float*)d_in[28];
  const float* bih  = (const float*)d_in[29];
  const float* bhh  = (const float*)d_in[30];
  const float* fcw  = (const float*)d_in[31];
  const float* fcb  = (const float*)d_in[32];
  float* out = (float*)d_out;

  float* ws = (float*)d_ws;
  size_t off = 0;
  float* pooled = ws + off; off += (size_t)NIMG*6400;      // 131 MB premax / raw conv2
  float* feats  = ws + off; off += (size_t)NIMG*FEAT;
  float* x1     = ws + off; off += (size_t)NIMG*64;
  float* x2     = ws + off; off += (size_t)NIMG*32;
  float* wlT    = ws + off; off += 39424;
  float* wrT    = ws + off; off += 39424;
  float* wl2T   = ws + off; off += 2048;
  float* wr2T   = ws + off; off += 2048;
  float* wihT   = ws + off; off += 8192;
  float* whhT   = ws + off; off += 16384;
  float* w1vT   = ws + off; off += 720;
  float* w1cT   = ws + off; off += 144;
  float* w2vT   = ws + off; off += 2304;
  float* w2cT   = ws + off; off += 1152;
  off = (off + 1) & ~(size_t)1;                            // 8B align for doubles
  double* stats = (double*)(ws + off); off += 2560;        // 1280 doubles
  int* row_start= (int*)(ws + off); off += 513;
  int* adj      = (int*)(ws + off); off += 8192;
  (void)in_sizes; (void)n_in; (void)out_size; (void)ws_size;

  prep_kernel<<<442, 256, 0, stream>>>(s1wl, s1wr, s2wl, s2wr, wih, whh,
                                       vw1, cw1, vw2, cw2,
                                       wlT, wrT, wl2T, wr2T, wihT, whhT,
                                       w1vT, w1cT, w2vT, w2cT, stats);
  csr_kernel<<<1, 512, 0, stream>>>(eidx, row_start, adj);

  double* stV1 = stats;        // veg BN1
  double* stV2 = stats + 320;  // veg BN2
  double* stC1 = stats + 640;  // cwsi BN1
  double* stC2 = stats + 960;  // cwsi BN2

  // --- veg CNN (single conv pass each; BN params inlined from stats) ---
  conv1_kernel<5><<<NIMG*3, 256, 0, stream>>>(veg, w1vT, stV1, pooled);
  conv2_kernel<16><<<NIMG, 256, 0, stream>>>(pooled, w2vT, stV1, vg1, vbe1, stV2);
  bnavg_kernel<16,0><<<NIMG, 256, 0, stream>>>(pooled, stV2, vg2, vbe2,
                                               irr, emb, feats, 0);

  // --- cwsi CNN ---
  conv1_kernel<1><<<NIMG*3, 256, 0, stream>>>(cwsi, w1cT, stC1, pooled);
  conv2_kernel<8><<<NIMG, 256, 0, stream>>>(pooled, w2cT, stC1, cg1, cbe1, stC2);
  bnavg_kernel<8,1><<<NIMG, 256, 0, stream>>>(pooled, stC2, cg2, cbe2,
                                              irr, emb, feats, 400);

  // --- features tail (agg fused into sage1; 4 rows/block — R10 config) ---
  sage1_kernel<<<NIMG/4, 256, 0, stream>>>(feats, row_start, adj, wlT, wrT, s1bl, x1);
  sage2_kernel<<<NIMG, 64, 0, stream>>>(x1, row_start, adj, wl2T, wr2T, s2bl, x2);
  lstm_kernel<<<NBATCH, 256, 0, stream>>>(x2, wihT, whhT, bih, bhh, fcw, fcb, out);
}